// Round 11
// baseline (225.911 us; speedup 1.0000x reference)
//
#include <hip/hip_runtime.h>
#include <hip/hip_fp16.h>

#define C  64
#define C8 8
#define NB 4
#define EPSV 1e-5f
// k = int(0.6*64) = 38 -> threshold = 38th largest = ascending index 26

__device__ __forceinline__ float silu_f(float v) {
    return v * (1.f / (1.f + __expf(-v)));
}

// Round-11: producer/consumer wave specialization (de-correlate stalls).
//
// Closed arc (r0..r10): {MLP<->VGPR<->waves} is saturated at every lockstep
// operating point: 224r/8w/ILP=117us, 128r/16w/spill=144, 116r/16w/serial=186.
// All waves stall together (phase 1: loads) then compute together (phase 2:
// sort).  Fix: 512-thread block, waves 0-3 run r0's phase-1 (latency-bound)
// on band k while waves 4-7 run r0's phase-2 (VALU-bound) on band k-1 --
// independent waves co-schedule on a SIMD (m114), so consumer VALU fills
// producer stall cycles.  Block = 16-row slab = NB=4 bands of 4 rows;
// 5 pipeline stages vs 8 sequential phase-times.
//
// LDS: dbuf y1s + dbuf xs (fp16, chunk-XOR swizzle c&7, r0-validated) =
// 128 KB + wt 6.4 KB = 134.4 KB (gfx950 allows 160 KB/workgroup).
// 256 blocks = 1/CU; halo reuse is intra-block (same CU L1/L2).
// Natural register allocation (224-tier, the only no-spill fast tier);
// per-role live sets are subsets of r0's proven 224.
__global__ __launch_bounds__(512) void fused_kernel(
    const float* __restrict__ x, const float* __restrict__ w_dw,
    const float* __restrict__ g1, const float* __restrict__ be1,
    const float* __restrict__ mu1, const float* __restrict__ va1,
    const float* __restrict__ w1, const float* __restrict__ b1,
    const float* __restrict__ g2, const float* __restrict__ be2,
    const float* __restrict__ mu2, const float* __restrict__ va2,
    const float* __restrict__ w2, const float* __restrict__ b2,
    const float* __restrict__ alphap, float* __restrict__ out)
{
    __shared__ __align__(16) __half y1s[2][C * 256];   // 64 KB (dbuf)
    __shared__ __align__(16) __half xs [2][C * 256];   // 64 KB (dbuf)
    __shared__ float wt[C * 25];                       // 6.4 KB

    const int blk = blockIdx.x;        // 256 = b*64 + d*4 + hq
    const int hq  = blk & 3;           // 16-row slab index
    const int d   = (blk >> 2) & 15;
    const int b   = blk >> 6;
    const int tid = threadIdx.x;

    for (int i = tid; i < C * 25; i += 512) wt[i] = w_dw[i];
    __syncthreads();

    const bool producer = (tid < 256);

    // producer constants (r0 phase-1 mapping on tid 0..255)
    const int c     = (tid & 255) >> 2;    // 0..63
    const int strip = tid & 3;
    const int q     = (strip * 16) >> 2;
    const int csw   = c & 7;               // chunk-XOR term
    const float scale = g1[c] * rsqrtf(va1[c] + EPSV);
    const float shift = be1[c] - mu1[c] * scale;
    const long  xbase = ((long)(b * C + c) * 16 + d) * 4096;

    // consumer constants (r0 phase-2 mapping on ctid 0..255)
    const int ctid = tid & 255;

    for (int k = 0; k <= NB; ++k) {
        if (producer) {
            if (k < NB) {
                // ---------- produce band k: conv rows h0..h0+3 -> y1s/xs[k&1]
                const int h0 = hq * 16 + k * 4;
                __half* y1p = y1s[k & 1];
                __half* xsp = xs [k & 1];

                float acc[4][16];
#pragma unroll
                for (int i = 0; i < 4; ++i)
#pragma unroll
                    for (int ow = 0; ow < 16; ++ow) acc[i][ow] = 0.f;

#pragma unroll
                for (int j = 0; j < 8; ++j) {   // input row r = h0 + j - 2
                    const int r = h0 + j - 2;
                    if (r >= 0 && r < 64) {
                        const float4* rowp = (const float4*)(x + xbase + r * 64);
                        const float4 z = make_float4(0.f, 0.f, 0.f, 0.f);
                        float4 u0 = (q > 0)  ? rowp[q - 1] : z;
                        float4 u1 = rowp[q];
                        float4 u2 = rowp[q + 1];
                        float4 u3 = rowp[q + 2];
                        float4 u4 = rowp[q + 3];
                        float4 u5 = (q < 12) ? rowp[q + 4] : z;
                        // vals[v] = x[row r, col strip*16 - 4 + v]
                        float vals[24] = {u0.x,u0.y,u0.z,u0.w, u1.x,u1.y,u1.z,u1.w,
                                          u2.x,u2.y,u2.z,u2.w, u3.x,u3.y,u3.z,u3.w,
                                          u4.x,u4.y,u4.z,u4.w, u5.x,u5.y,u5.z,u5.w};
                        if (j >= 2 && j <= 5) {   // band rows: stage x -> xs
                            const int i = j - 2;
                            const int chunkbase = i * 8 + 2 * strip;
#pragma unroll
                            for (int t = 0; t < 2; ++t) {
                                const int p = (chunkbase + t) ^ csw;
                                union { __half2 h[4]; float4 f; } u;
#pragma unroll
                                for (int m = 0; m < 4; ++m)
                                    u.h[m] = __floats2half2_rn(vals[4 + t * 8 + 2 * m],
                                                               vals[4 + t * 8 + 2 * m + 1]);
                                *(float4*)&xsp[c * 256 + p * 8] = u.f;
                            }
                        }
#pragma unroll
                        for (int i = 0; i < 4; ++i) {
                            if (i <= j && (j - i) <= 4) {   // kernel row kr = j-i
                                const int kr = j - i;
                                const float* wrow = &wt[c * 25 + kr * 5];
#pragma unroll
                                for (int kc = 0; kc < 5; ++kc) {
                                    const float kw = wrow[kc];
#pragma unroll
                                    for (int ow = 0; ow < 16; ++ow)
                                        acc[i][ow] += kw * vals[ow + kc + 2];
                                }
                            }
                        }
                    }
                }
#pragma unroll
                for (int i = 0; i < 4; ++i) {
                    float o[16];
#pragma unroll
                    for (int ow = 0; ow < 16; ++ow)
                        o[ow] = silu_f(acc[i][ow] * scale + shift);
                    const int chunkbase = i * 8 + 2 * strip;
#pragma unroll
                    for (int t = 0; t < 2; ++t) {
                        const int p = (chunkbase + t) ^ csw;
                        union { __half2 h[4]; float4 f; } u;
#pragma unroll
                        for (int m = 0; m < 4; ++m)
                            u.h[m] = __floats2half2_rn(o[t * 8 + 2 * m],
                                                       o[t * 8 + 2 * m + 1]);
                        *(float4*)&y1p[c * 256 + p * 8] = u.f;
                    }
                }
            }
        } else {
            if (k > 0) {
                // ---------- consume band k-1: pw1+BN2+SiLU+pw2, top-k, epilogue
                const int kk  = k - 1;
                const int h0  = hq * 16 + kk * 4;
                const __half* y1p = y1s[kk & 1];
                const __half* xsp = xs [kk & 1];
                const int loc = ctid;

                // pw1 from LDS xs
                float s1[C8];
#pragma unroll
                for (int o = 0; o < C8; ++o) s1[o] = 0.f;
#pragma unroll
                for (int cc = 0; cc < C; ++cc) {
                    const float xc = __half2float(xsp[cc * 256 + (loc ^ ((cc & 7) << 3))]);
#pragma unroll
                    for (int o = 0; o < C8; ++o) s1[o] += w1[o * C + cc] * xc;
                }
                float hh[C8];
#pragma unroll
                for (int o = 0; o < C8; ++o) {
                    const float sc = g2[o] * rsqrtf(va2[o] + EPSV);
                    hh[o] = silu_f((s1[o] + b1[o] - mu2[o]) * sc + be2[o]);
                }

                // attn values (sort scratch; epilogue recomputes identically)
                float t[C];
#pragma unroll
                for (int cc = 0; cc < C; ++cc) {
                    const float y1v = __half2float(y1p[cc * 256 + (loc ^ ((cc & 7) << 3))]);
                    float y2 = b2[cc];
#pragma unroll
                    for (int o = 0; o < C8; ++o) y2 += w2[cc * C8 + o] * hh[o];
                    t[cc] = y1v * y2;
                }

                // in-register bitonic sort (ascending) of 64 — shuffle-free
#pragma unroll
                for (int kb = 2; kb <= 64; kb <<= 1) {
#pragma unroll
                    for (int j = kb >> 1; j > 0; j >>= 1) {
#pragma unroll
                        for (int i = 0; i < 64; ++i) {
                            const int l = i ^ j;
                            if (l > i) {
                                const float u = t[i], v = t[l];
                                const float mn = fminf(u, v), mx = fmaxf(u, v);
                                if ((i & kb) == 0) { t[i] = mn; t[l] = mx; }
                                else               { t[i] = mx; t[l] = mn; }
                            }
                        }
                    }
                }
                const float thr = t[26];          // 38th largest of 64
                const float alpha = alphap[0];

                const int  rg   = d * 4096 + (h0 + (ctid >> 6)) * 64 + (ctid & 63);
                const long ooff = (long)b * (C * 65536) + rg;

                // epilogue: recompute attn (identical FMA order -> bitwise
                // equal to sorted values); x residual from xs; coalesced stores
#pragma unroll
                for (int cc = 0; cc < C; ++cc) {
                    const float y1v = __half2float(y1p[cc * 256 + (loc ^ ((cc & 7) << 3))]);
                    float y2 = b2[cc];
#pragma unroll
                    for (int o = 0; o < C8; ++o) y2 += w2[cc * C8 + o] * hh[o];
                    const float av = y1v * y2;
                    const float xc = __half2float(xsp[cc * 256 + (loc ^ ((cc & 7) << 3))]);
                    out[ooff + (long)cc * 65536] = xc + ((av >= thr) ? alpha * av : 0.f);
                }
            }
        }
        __syncthreads();   // block-uniform: one barrier per pipeline stage
    }
}

extern "C" void kernel_launch(void* const* d_in, const int* in_sizes, int n_in,
                              void* d_out, int out_size, void* d_ws, size_t ws_size,
                              hipStream_t stream) {
    const float* x    = (const float*)d_in[0];
    const float* w_dw = (const float*)d_in[1];
    const float* g1   = (const float*)d_in[2];
    const float* be1  = (const float*)d_in[3];
    const float* mu1  = (const float*)d_in[4];
    const float* va1  = (const float*)d_in[5];
    const float* w1   = (const float*)d_in[6];
    const float* b1   = (const float*)d_in[7];
    const float* g2   = (const float*)d_in[8];
    const float* be2  = (const float*)d_in[9];
    const float* mu2  = (const float*)d_in[10];
    const float* va2  = (const float*)d_in[11];
    const float* w2   = (const float*)d_in[12];
    const float* b2   = (const float*)d_in[13];
    const float* alp  = (const float*)d_in[14];
    float* out = (float*)d_out;

    // grid: b(4) x d(16) x slab(4) = 256 blocks of 512 threads = 1 block/CU
    fused_kernel<<<256, 512, 0, stream>>>(
        x, w_dw, g1, be1, mu1, va1, w1, b1, g2, be2, mu2, va2, w2, b2, alp, out);
}